// Round 10
// baseline (1814.923 us; speedup 1.0000x reference)
//
#include <hip/hip_runtime.h>
#include <hip/hip_bf16.h>

// ---------------------------------------------------------------------------
// Encoder: emb gather -> LSTM0 -> LSTM1 -> BatchNorm(inference)
// B=64, T=128, D=256, H=1024, 4H=4096, BT=8192 rows.
//
// Round-10 structure (r9 + cheaper sync + latency hiding):
//  - Layers are STRICTLY sequential (L1 initial state = L0 final state, per
//    reference) -> two persistent dispatches, 128 rounds each.
//  - 128 WGs x 256 thr (1 WG/CU, 149KB LDS). WG = (g = bid&1 row-half of 32)
//    x (ws = bid>>1: 64-pc slice = 16 j). U slice 128KB in LDS. Waves =
//    (nt pc-half) x (kh K-half); 32 MFMAs/wave; A (h) global->reg 32x16B.
//  - Barrier: NO leader/root hops (r9 lesson: each hop ~0.9us at HBM-atomic
//    latency). Arrival: 1 relaxed agent RMW on line bid%8 (16 arrivals/line).
//    Detect: poller sums the 4 lines of its g-parity directly.
//  - XW(t+1) prefetched into regs during step t (XW constant -> load can
//    float; removes HBM latency from the z-chain).
//  - outp/BN stores issued AFTER arrival, BEFORE poll; release point is raw
//    `s_barrier` asm (NOT __syncthreads -> no vmcnt(0) drain of those stores).
//  - h exchange: hall[t] slots, agent-scope atomic stores (proven r6-r9),
//    wave0-only drain (h-store threads all in wave 0) then arrive.
// ---------------------------------------------------------------------------

typedef __attribute__((ext_vector_type(8))) short short8;
typedef __attribute__((ext_vector_type(4))) short short4v;
typedef __attribute__((ext_vector_type(4))) float f32x4;
typedef __attribute__((ext_vector_type(16))) float f32x16;
typedef unsigned short ushort_t;

__device__ __forceinline__ void lgkm0_bar() {
  asm volatile("s_waitcnt lgkmcnt(0)" ::: "memory");
  __builtin_amdgcn_s_barrier();
}

__device__ __forceinline__ ushort_t f2b(float f) {
  __hip_bfloat16 h = __float2bfloat16(f);
  return *reinterpret_cast<ushort_t*>(&h);
}
__device__ __forceinline__ float b2f(ushort_t u) {
  unsigned int x = ((unsigned int)u) << 16;
  return __builtin_bit_cast(float, x);
}
__device__ __forceinline__ float fsigmoid(float x) {
  return 1.f / (1.f + __expf(-x));
}
__device__ __forceinline__ float ftanh(float x) {
  return 1.f - 2.f / (__expf(2.f * x) + 1.f);
}

__device__ __forceinline__ void gload_lds16(const ushort_t* g, ushort_t* l) {
  __builtin_amdgcn_global_load_lds(
      (const __attribute__((address_space(1))) unsigned int*)g,
      (__attribute__((address_space(3))) unsigned int*)l, 16, 0, 0);
}

// ---- convert W [K][4096] f32 -> [pc][k] bf16 (GEMM B-operand) -------------
__global__ __launch_bounds__(256) void k_convert(
    const float* __restrict__ src, ushort_t* __restrict__ dst, int kshift) {
  size_t tid = (size_t)blockIdx.x * 256 + threadIdx.x;  // = k*4096 + c
  int k = (int)(tid >> 12);
  int c = (int)(tid & 4095);
  int pc = ((c & 1023) << 2) | (c >> 10);
  dst[((size_t)pc << kshift) + k] = f2b(src[tid]);
}

// ---- convert U [1024][4096] f32 -> per-slice(64pc) MFMA-frag order --------
// chunk cid = ((((ws*2 + nt)*2 + kh)*32 + ks)*64 + l):
//   pc = ws*64 + nt*32 + (l&31), k = kh*512 + ks*16 + (l>>5)*8 + e
__global__ __launch_bounds__(256) void k_convert_u(
    const float* __restrict__ src, ushort_t* __restrict__ dst) {
  int cid = blockIdx.x * 256 + threadIdx.x;   // 524288 chunks
  int l = cid & 63;
  int ks = (cid >> 6) & 31;
  int kh = (cid >> 11) & 1;
  int nt = (cid >> 12) & 1;
  int ws = cid >> 13;                          // 0..63
  int pc = ws * 64 + nt * 32 + (l & 31);
  int c = ((pc & 3) << 10) | (pc >> 2);
  int k0 = kh * 512 + ks * 16 + (l >> 5) * 8;
  short8 v;
#pragma unroll
  for (int e = 0; e < 8; ++e)
    v[e] = (short)f2b(src[(size_t)(k0 + e) * 4096 + c]);
  *(short8*)(dst + (size_t)cid * 8) = v;
}

// ---- permute biases -------------------------------------------------------
__global__ __launch_bounds__(256) void k_bias(
    const float* __restrict__ b0, const float* __restrict__ b1,
    float* __restrict__ bp0, float* __restrict__ bp1) {
  int pc = blockIdx.x * 256 + threadIdx.x;
  int c = ((pc & 3) << 10) | (pc >> 2);
  bp0[pc] = b0[c];
  bp1[pc] = b1[c];
}

// ---- embedding gather: plain row-major Xef[8192][256] ---------------------
__global__ __launch_bounds__(256) void k_gather(
    const int* __restrict__ tokens, const float* __restrict__ emb,
    ushort_t* __restrict__ Xef) {
  int row = blockIdx.x;            // row = t*64 + b
  int t = row >> 6, b = row & 63;
  int tok = tokens[b * 128 + t];
  int d = threadIdx.x;
  Xef[(size_t)row * 256 + d] = f2b(emb[(size_t)tok * 256 + d]);
}

// ---- state init: h0 -> hall slot0 (plain); c0 -> c_st; zero barriers ------
__global__ __launch_bounds__(256) void k_init(
    const float* __restrict__ h0, const float* __restrict__ c0,
    ushort_t* __restrict__ hall, float* __restrict__ c_st,
    unsigned* __restrict__ bars) {
  int tid = blockIdx.x * 256 + threadIdx.x;
  c_st[tid] = c0[tid];
  hall[tid] = f2b(h0[tid]);
  if (tid < 512) bars[tid] = 0;
}

// ---- GEMM: C[8192][4096] = A[8192][K] * BT[4096][K]^T ---------------------
// A plain row-major (LAY=0: Xef [8192][256]; LAY=1: hall slots 1..128).
// 128x128 tile, global_load_lds staging, XCD-blocked (8 wgM inner, wgN outer).
template <int NKS, int LAY>
__global__ __launch_bounds__(256) void k_gemm(
    const ushort_t* __restrict__ Af, const ushort_t* __restrict__ BT,
    ushort_t* __restrict__ C) {
  const int K = NKS * 16;
  const int xcd = blockIdx.x & 7, loc = blockIdx.x >> 3;
  const int wgM = xcd * 8 + (loc & 7);
  const int wgN = loc >> 3;
  const int tid = threadIdx.x;
  const int l = tid & 63;
  const int wv = tid >> 6;
  const int wvM = wv & 1, wvN = wv >> 1;

  __shared__ __align__(16) ushort_t Alds[4096];
  __shared__ __align__(16) ushort_t Blds[4096];

  const int m0 = wgM * 128, n0 = wgN * 128;
  f32x4 acc[4][4] = {};

  for (int k0 = 0; k0 < K; k0 += 32) {
    __syncthreads();
#pragma unroll
    for (int jj = 0; jj < 2; ++jj) {
      int c = jj * 256 + tid;
      int kc = c >> 7, r = c & 127;
      int R = m0 + r;
      int kcg = (k0 >> 3) + kc;
      const ushort_t* asrc =
          (LAY == 0) ? (Af + (size_t)R * 256 + kcg * 8)
                     : (Af + (size_t)(R >> 6) * 65536 + (R & 63) * 1024 + kcg * 8);
      gload_lds16(asrc, (ushort_t*)&Alds[(size_t)(jj * 256 + (tid & ~63)) * 8]);
      gload_lds16(BT + (size_t)(n0 + r) * K + k0 + kc * 8,
                  (ushort_t*)&Blds[(size_t)(jj * 256 + (tid & ~63)) * 8]);
    }
    __syncthreads();

    short8 af[4], bf[4];
#pragma unroll
    for (int mt = 0; mt < 4; ++mt)
      af[mt] = *(const short8*)&Alds[((l >> 4) * 128 + wvM * 64 + mt * 16 + (l & 15)) * 8];
#pragma unroll
    for (int nt = 0; nt < 4; ++nt)
      bf[nt] = *(const short8*)&Blds[((l >> 4) * 128 + wvN * 64 + nt * 16 + (l & 15)) * 8];
#pragma unroll
    for (int mt = 0; mt < 4; ++mt)
#pragma unroll
      for (int nt = 0; nt < 4; ++nt)
        acc[mt][nt] =
            __builtin_amdgcn_mfma_f32_16x16x32_bf16(af[mt], bf[nt], acc[mt][nt], 0, 0, 0);
  }

  const int rr0 = wgM * 128 + wvM * 64 + (l >> 4) * 4;
  const int cc0 = wgN * 128 + wvN * 64 + (l & 15);
#pragma unroll
  for (int mt = 0; mt < 4; ++mt)
#pragma unroll
    for (int nt = 0; nt < 4; ++nt)
#pragma unroll
      for (int r = 0; r < 4; ++r)
        C[(size_t)(rr0 + mt * 16 + r) * 4096 + cc0 + nt * 16] =
            f2b(acc[mt][nt][r]);
}

// ---- persistent LSTM layer (128 steps), plain launch <<<128,256>>> --------
// bid -> g = bid&1 (row half, independent subgrid), ws = bid>>1 (64-pc slice).
// Waves (nt = wv&1 pc-half, kh = wv>>1 K-half). U from LDS, A global->reg.
template <int LAYER>
__global__ __launch_bounds__(256, 1) void k_pers(
    const ushort_t* __restrict__ Uf,    // slice-frag order (k_convert_u)
    const ushort_t* __restrict__ XW,    // [8192][4096] bf16 row-major
    const float* __restrict__ bp,       // [4096] permuted bias
    ushort_t* __restrict__ hall,        // 129 slots x [64][1024] bf16
    float* __restrict__ c_st,           // [64][1024] f32
    float* __restrict__ outp,           // L1: d_out
    const float* __restrict__ gamma, const float* __restrict__ beta,
    const float* __restrict__ mean, const float* __restrict__ var,
    unsigned* __restrict__ bar) {
  const int bid = blockIdx.x;
  const int g = bid & 1;                  // row half (independent chain)
  const int ws = bid >> 1;                // pc-slice 0..63 (64 pc = 16 j)
  const int tid = threadIdx.x;
  const int l = tid & 63;
  const int wv = tid >> 6;
  const int nt = wv & 1, kh = wv >> 1;

  __shared__ __align__(16) ushort_t Ulds[65536];   // 128 KB U slice
  __shared__ float zls[2][2][32][33];              // 16.9 KB K-reduce
  __shared__ ushort_t hbuf[32][16];                // 1 KB h assembly

  // ---- stage U slice into LDS (8192 x 16B, coalesced, once) ----
  {
    const ushort_t* src = Uf + (size_t)ws * 65536;
    for (int i = tid; i < 8192; i += 256)
      *(short8*)(Ulds + (size_t)i * 8) = *(const short8*)(src + (size_t)i * 8);
  }

  // ---- epilogue constants: thread owns (row_o, jp) x q in {0,1} ----
  const int row_o = tid & 31, jp = tid >> 5;   // jp 0..7
  const int rowg = g * 32 + row_o;
  float creg[2], scl[2], sft[2];
#pragma unroll
  for (int q = 0; q < 2; ++q) {
    int j = ws * 16 + jp * 2 + q;
    creg[q] = c_st[rowg * 1024 + j];
    if (LAYER == 1) {
      float inv = rsqrtf(var[j] + 1e-3f);
      scl[q] = inv * gamma[j];
      sft[q] = beta[j] - mean[j] * scl[q];
    }
  }
  const f32x4 bias0 = *(const f32x4*)(bp + ws * 64 + jp * 8);
  const f32x4 bias1 = *(const f32x4*)(bp + ws * 64 + jp * 8 + 4);

  // first-step XW prefetch (XW is constant data -> can float freely)
  short8 xwn = *(const short8*)(
      XW + ((size_t)(0 * 64 + rowg) << 12) + ws * 64 + jp * 8);

  __syncthreads();   // Ulds visible

#pragma unroll 1
  for (int t = 0; t < 128; ++t) {
    const ushort_t* hin =
        hall + (size_t)((LAYER == 1 && t == 0) ? 128 : t) * 65536;
    ushort_t* hout = hall + (size_t)(t + 1) * 65536;

    // ---- A: 32 back-to-back 16B loads (rows of my g-half, my K-half) ----
    const ushort_t* ab =
        hin + (size_t)(g * 32 + (l & 31)) * 1024 + kh * 512 + (l >> 5) * 8;
    short8 ar[32];
#pragma unroll
    for (int ks = 0; ks < 32; ++ks)
      ar[ks] = *(const short8*)(ab + ks * 16);

    // ---- 32 MFMAs: A reg, B from LDS (1KB-contiguous ds_read_b128) ----
    const ushort_t* uB = Ulds + (size_t)(nt * 2 + kh) * 16384;
    f32x16 acc0 = {}, acc1 = {}, acc2 = {}, acc3 = {};
#pragma unroll
    for (int ks = 0; ks < 32; ks += 4) {
      short8 b0 = *(const short8*)(uB + (size_t)(ks + 0) * 512 + l * 8);
      short8 b1 = *(const short8*)(uB + (size_t)(ks + 1) * 512 + l * 8);
      short8 b2 = *(const short8*)(uB + (size_t)(ks + 2) * 512 + l * 8);
      short8 b3 = *(const short8*)(uB + (size_t)(ks + 3) * 512 + l * 8);
      acc0 = __builtin_amdgcn_mfma_f32_32x32x16_bf16(ar[ks + 0], b0, acc0, 0, 0, 0);
      acc1 = __builtin_amdgcn_mfma_f32_32x32x16_bf16(ar[ks + 1], b1, acc1, 0, 0, 0);
      acc2 = __builtin_amdgcn_mfma_f32_32x32x16_bf16(ar[ks + 2], b2, acc2, 0, 0, 0);
      acc3 = __builtin_amdgcn_mfma_f32_32x32x16_bf16(ar[ks + 3], b3, acc3, 0, 0, 0);
    }
    f32x16 zt = (acc0 + acc1) + (acc2 + acc3);

    // ---- K-partials to LDS (32x32 C layout) ----
#pragma unroll
    for (int r = 0; r < 16; ++r)
      zls[kh][nt][(r & 3) + 8 * (r >> 2) + 4 * (l >> 5)][l & 31] = zt[r];
    lgkm0_bar();

    // ---- epilogue: 2-way K-sum, gates, c-update ----
    float hn2[2];
#pragma unroll
    for (int q = 0; q < 2; ++q) {
      const int j_o = jp * 2 + q;
      const int nte = j_o >> 3;
      const int cb = (j_o & 7) * 4;
      f32x4 zv0 = *(const f32x4*)&zls[0][nte][row_o][cb];
      f32x4 zv1 = *(const f32x4*)&zls[1][nte][row_o][cb];
      const f32x4& bv = q ? bias1 : bias0;
      float zi = zv0[0] + zv1[0] + b2f((ushort_t)xwn[q * 4 + 0]) + bv[0];
      float zf = zv0[1] + zv1[1] + b2f((ushort_t)xwn[q * 4 + 1]) + bv[1];
      float zg = zv0[2] + zv1[2] + b2f((ushort_t)xwn[q * 4 + 2]) + bv[2];
      float zo = zv0[3] + zv1[3] + b2f((ushort_t)xwn[q * 4 + 3]) + bv[3];
      float ii = fsigmoid(zi), ff = fsigmoid(zf), oo = fsigmoid(zo);
      float gg = ftanh(zg);
      creg[q] = ff * creg[q] + ii * gg;
      hn2[q] = oo * ftanh(creg[q]);
      hbuf[row_o][j_o] = f2b(hn2[q]);
    }
    lgkm0_bar();   // hbuf ready (also: zls reads done before next overwrite)

    // ---- h out (wave 0 only: 64 threads x 16B, agent-scope) ----
    if (tid < 64) {
      const int row = tid >> 1, half = tid & 1;
      short8 v = *(const short8*)&hbuf[row][half * 8];
      union { short8 s; unsigned u[4]; } cv;
      cv.s = v;
      unsigned* dst =
          (unsigned*)(hout + (size_t)(g * 32 + row) * 1024 + ws * 16 + half * 8);
#pragma unroll
      for (int wi = 0; wi < 4; ++wi)
        __hip_atomic_store(dst + wi, cv.u[wi], __ATOMIC_RELAXED,
                           __HIP_MEMORY_SCOPE_AGENT);
    }

    // ---- drain h-stores (all h-store lanes are in wave 0), arrive ----
    asm volatile("s_waitcnt vmcnt(0)" ::: "memory");
    if (tid == 0)
      __hip_atomic_fetch_add(bar + (bid & 7) * 16, 1u, __ATOMIC_RELAXED,
                             __HIP_MEMORY_SCOPE_AGENT);

    // ---- poll window: issue outp/BN stores + next XW prefetch ----
    if (LAYER == 1) {
#pragma unroll
      for (int q = 0; q < 2; ++q) {
        int j = ws * 16 + jp * 2 + q;
        outp[((size_t)rowg * 128 + t) * 1024 + j] = hn2[q] * scl[q] + sft[q];
        if (t == 127) {
          outp[8388608 + rowg * 1024 + j] = hn2[q];
          outp[8454144 + rowg * 1024 + j] = creg[q];
        }
      }
    } else if (t == 127) {
#pragma unroll
      for (int q = 0; q < 2; ++q)
        c_st[rowg * 1024 + ws * 16 + jp * 2 + q] = creg[q];
    }
    if (t < 127)
      xwn = *(const short8*)(
          XW + ((size_t)((t + 1) * 64 + rowg) << 12) + ws * 64 + jp * 8);

    // ---- detect: sum the 4 lines of my g-parity (no leader hops) ----
    if (tid == 0) {
      const unsigned tgt = 64u * (unsigned)(t + 1);
      for (;;) {
        unsigned s = 0;
#pragma unroll
        for (int i = 0; i < 4; ++i)
          s += __hip_atomic_load(bar + (g + 2 * i) * 16, __ATOMIC_RELAXED,
                                 __HIP_MEMORY_SCOPE_AGENT);
        if (s >= tgt) break;
        __builtin_amdgcn_s_sleep(1);
      }
    }
    asm volatile("s_barrier" ::: "memory");   // release (no vmcnt drain)
  }
}

extern "C" void kernel_launch(void* const* d_in, const int* in_sizes, int n_in,
                              void* d_out, int out_size, void* d_ws,
                              size_t ws_size, hipStream_t stream) {
  const int* tokens = (const int*)d_in[0];
  const float* h0 = (const float*)d_in[1];
  const float* c0 = (const float*)d_in[2];
  const float* emb = (const float*)d_in[3];
  const float* W0 = (const float*)d_in[4];
  const float* U0 = (const float*)d_in[5];
  const float* b0 = (const float*)d_in[6];
  const float* W1 = (const float*)d_in[7];
  const float* U1 = (const float*)d_in[8];
  const float* b1 = (const float*)d_in[9];
  const float* gammap = (const float*)d_in[10];
  const float* betap = (const float*)d_in[11];
  const float* mmean = (const float*)d_in[12];
  const float* mvar = (const float*)d_in[13];

  char* ws = (char*)d_ws;
  ushort_t* Uc0 = (ushort_t*)(ws + 0);             //  8 MB slice-frag U0
  ushort_t* Uc1 = (ushort_t*)(ws + 8388608);       //  8 MB slice-frag U1
  ushort_t* W0f = (ushort_t*)(ws + 16777216);      //  2 MB [pc][256]
  ushort_t* W1f = (ushort_t*)(ws + 18874368);      //  8 MB [pc][1024]
  float* bp0 = (float*)(ws + 27262976);            // 16 KB
  float* bp1 = (float*)(ws + 27279360);            // 16 KB
  ushort_t* Xef = (ushort_t*)(ws + 27295744);      //  4 MB [8192][256]
  ushort_t* XW = (ushort_t*)(ws + 31490048);       // 64 MB [8192][4096]
  ushort_t* hall = (ushort_t*)(ws + 98598912);     // 16.5 MB: 129 x 128KB
  float* c_st = (float*)(ws + 115507200);          // 256 KB
  unsigned* bars = (unsigned*)(ws + 115769344);    // 2 KB

  k_convert_u<<<2048, 256, 0, stream>>>(U0, Uc0);
  k_convert_u<<<2048, 256, 0, stream>>>(U1, Uc1);
  k_convert<<<4096, 256, 0, stream>>>(W0, W0f, 8);
  k_convert<<<16384, 256, 0, stream>>>(W1, W1f, 10);
  k_bias<<<16, 256, 0, stream>>>(b0, b1, bp0, bp1);
  k_gather<<<8192, 256, 0, stream>>>(tokens, emb, Xef);
  k_init<<<256, 256, 0, stream>>>(h0, c0, hall, c_st, bars);

  float* outp = (float*)d_out;

  // ---- layer 0 ----
  k_gemm<16, 0><<<2048, 256, 0, stream>>>(Xef, W0f, XW);
  k_pers<0><<<128, 256, 0, stream>>>(Uc0, XW, bp0, hall, c_st, nullptr,
                                     nullptr, nullptr, nullptr, nullptr,
                                     bars);

  // ---- layer 1 (GEMM A = hall slots 1..128 = L0 outputs) ----
  k_gemm<64, 1><<<2048, 256, 0, stream>>>(hall + 65536, W1f, XW);
  k_pers<1><<<128, 256, 0, stream>>>(Uc1, XW, bp1, hall, c_st, outp, gammap,
                                     betap, mmean, mvar, bars + 128);
}